// Round 1
// 247.974 us; speedup vs baseline: 1.0180x; 1.0180x over previous
//
#include <hip/hip_runtime.h>

// CRF forward partition, MI355X. B=1024, L=512, T=52.
//
// p-space recurrence: p_new[j] = exp(f[t,j]) * sum_i E[i][j]*p[i],
// E = exp(transitions), constant. One wave per batch; lane j owns tag j.
//
// R7 vs R6: replace the 52x v_readlane lane->SGPR broadcast (104+ cyc issue
// + VALU-writes-SGPR hazard fences) with an LDS broadcast:
//   - lane j writes pv to plds[j]            (1x ds_write_b32)
//   - all lanes read p back as 13 uniform-address float4 loads
//     (ds_read_b128, same-address broadcast => conflict-free)
//   - fmacs consume p as VGPR quads (VGPR x VGPR, no SGPR hazards)
// DS ops within a wave are in-order => write->read RAW needs no waitcnt;
// compiler emits fine-grained lgkmcnt(N) before each fmac use, so the
// first quad's fmacs overlap the remaining reads' latency.
// All sched_barrier fences removed (they existed only for the SGPR hazard).
// Arithmetic is bit-identical to R6 (same operand values, same add order,
// same once-per-NS lane-0 normalization).

#define TT 52   // TAG_SIZE
#define LL 512  // sequence length
#define NS 8    // steps per group; normalize once per group

__device__ __forceinline__ float rl(float x, int lane) {
    return __int_as_float(__builtin_amdgcn_readlane(__float_as_int(x), lane));
}

__global__ void __launch_bounds__(64)
__attribute__((amdgpu_waves_per_eu(1, 1)))
crf_fwd(
    const float* __restrict__ feats,   // (B, L, T)
    const int*   __restrict__ mask,    // (B, L)
    const float* __restrict__ trans,   // (T, T)
    float*       __restrict__ out)     // scalar accumulator (pre-zeroed)
{
    __shared__ __align__(16) float plds[64];

    const int b = blockIdx.x;
    const int j = threadIdx.x;          // lane = destination tag
    const bool act = (j < TT);
    const int jc = act ? j : 0;         // clamped index for safe loads

    const float* fb = feats + (size_t)b * LL * TT;
    const int*   mb = mask  + (size_t)b * LL;

    // Per-lane transition column: E[i] = exp(trans[i][j]).
    // -1000 entries (START col / END row) become exact 0.
    float E[TT];
#pragma unroll
    for (int i = 0; i < TT; ++i) {
        float e = __expf(trans[i * TT + jc]);
        E[i] = act ? e : 0.0f;
    }

    // t=0 init: part0[j] = feats[b,0,j] + trans[START][j]; normalize by lane 0.
    float part0 = act ? (fb[j] + trans[(TT - 2) * TT + j]) : -1.0e30f;
    float shift = rl(part0, 0);
    float pv = act ? __expf(part0 - shift) : 0.0f;   // lane j holds p[j]

    plds[j] = pv;   // seed broadcast buffer (lanes >= TT write 0.0)

    const float4* pq = (const float4*)plds;   // 13 quads cover tags 0..51

    // Prefetch ring (always in-bounds; no guard branches).
    float fpre[NS];
    int   mc[NS];
#pragma unroll
    for (int u = 0; u < NS; ++u) {
        int t = 1 + u;                  // all < LL
        fpre[u] = fb[t * TT + jc];
        mc[u]   = mb[t];
    }

    // Main loop: 63 groups of 8 covering t = 1 .. 504; tail 505..511.
    for (int t0 = 1; t0 + NS <= LL; t0 += NS) {
        // next group's loads first (8 steps of latency slack)
        float fnx[NS];
        int   mn[NS];
#pragma unroll
        for (int u = 0; u < NS; ++u) {
            int tn = t0 + NS + u;
            int tcl = tn < LL ? tn : (LL - 1);   // clamp (tail overrun harmless)
            fnx[u] = fb[tcl * TT + jc];
            mn[u]  = mb[tcl];
        }

        // ef for the whole group upfront: independent of the recurrence chain
        float ef[NS];
#pragma unroll
        for (int u = 0; u < NS; ++u) ef[u] = __expf(fpre[u]);

#pragma unroll
        for (int u = 0; u < NS; ++u) {
            // s_j = sum_i E[i][j] * p[i]; p arrives as broadcast LDS quads.
            // Reads issue in order => fmacs on q0 start while q1..q12 fly.
            float a0 = 0.f, a1 = 0.f, a2 = 0.f, a3 = 0.f;
#pragma unroll
            for (int k = 0; k < TT / 4; ++k) {
                float4 q = pq[k];
                a0 = fmaf(q.x, E[4 * k + 0], a0);
                a1 = fmaf(q.y, E[4 * k + 1], a1);
                a2 = fmaf(q.z, E[4 * k + 2], a2);
                a3 = fmaf(q.w, E[4 * k + 3], a3);
            }
            float pn = ((a0 + a1) + (a2 + a3)) * ef[u];
            pv = (mc[u] > 0) ? pn : pv;          // branchless mask select
            if (u == NS - 1) {
                // normalize once per group by lane 0 (>0 always); track shift
                float c = rl(pv, 0);
                shift += __logf(c);
                pv *= __builtin_amdgcn_rcpf(c);
            }
            plds[j] = pv;   // broadcast for next step (in-order DS => no sync)
        }
#pragma unroll
        for (int u = 0; u < NS; ++u) { fpre[u] = fnx[u]; mc[u] = mn[u]; }
    }

    // Tail: t = 505..511 (7 steps, data already in fpre[0..6]).
#pragma unroll
    for (int u = 0; u < 7; ++u) {
        float efu = __expf(fpre[u]);
        float a0 = 0.f, a1 = 0.f, a2 = 0.f, a3 = 0.f;
#pragma unroll
        for (int k = 0; k < TT / 4; ++k) {
            float4 q = pq[k];
            a0 = fmaf(q.x, E[4 * k + 0], a0);
            a1 = fmaf(q.y, E[4 * k + 1], a1);
            a2 = fmaf(q.z, E[4 * k + 2], a2);
            a3 = fmaf(q.w, E[4 * k + 3], a3);
        }
        float pn = ((a0 + a1) + (a2 + a3)) * efu;
        pv = (mc[u] > 0) ? pn : pv;
        plds[j] = pv;
    }

    // Final: log(sum_i exp(trans[i][END]) * p[i]) + shift
    float eend = __expf(trans[jc * TT + (TT - 1)]);
    float val = act ? (eend * pv) : 0.0f;
#pragma unroll
    for (int o = 32; o >= 1; o >>= 1)
        val += __shfl_xor(val, o, 64);
    if (j == 0) atomicAdd(out, __logf(val) + shift);
}

extern "C" void kernel_launch(void* const* d_in, const int* in_sizes, int n_in,
                              void* d_out, int out_size, void* d_ws, size_t ws_size,
                              hipStream_t stream) {
    const float* feats = (const float*)d_in[0];
    const int*   mask  = (const int*)d_in[1];
    const float* trans = (const float*)d_in[2];
    float* out = (float*)d_out;

    const int B = in_sizes[1] / LL;   // mask is (B, L)

    hipMemsetAsync(d_out, 0, sizeof(float), stream);
    crf_fwd<<<B, 64, 0, stream>>>(feats, mask, trans, out);
}

// Round 2
// 243.549 us; speedup vs baseline: 1.0365x; 1.0182x over previous
//
#include <hip/hip_runtime.h>

// CRF forward partition, MI355X. B=1024, L=512, T=52.
//
// R8: forward/backward split for in-wave ILP.
// The recurrence is linear in p-space: p_t = D_t E^T p_{t-1} (masked step =
// identity), output = eend^T M_511...M_1 p0. Evaluate from both ends:
//   fwd:  u  = M_256...M_1 p0          (t = 1..256,   column-matvec vs E)
//   bwd:  w <- E (ef_t (*) w)          (t = 511..257, row-matvec vs E)
//   out:  log(sum_i w[i]*u[i]) + shiftF + shiftB
// Two independent chains interleaved in one wave fill the ~50% dependency
// stalls R6/R7 proved are latency (not issue) bound: serial depth 512 -> 256.
// Broadcasts stay in LDS (R7): write at step START (p for fwd, ef*w for bwd),
// read back as uniform-address float4 quads (in-order DS, no sync needed).

#define TT 52   // TAG_SIZE
#define LL 512  // sequence length
#define NS 8    // pairs per group; normalize once per group

__device__ __forceinline__ float rl(float x, int lane) {
    return __int_as_float(__builtin_amdgcn_readlane(__float_as_int(x), lane));
}

__global__ void __launch_bounds__(64)
__attribute__((amdgpu_waves_per_eu(1, 1)))
crf_fwd(
    const float* __restrict__ feats,   // (B, L, T)
    const int*   __restrict__ mask,    // (B, L)
    const float* __restrict__ trans,   // (T, T)
    float*       __restrict__ out)     // scalar accumulator (pre-zeroed)
{
    __shared__ __align__(16) float plds[128];   // [0:64) fwd p, [64:128) bwd v

    const int b = blockIdx.x;
    const int j = threadIdx.x;          // lane = tag
    const bool act = (j < TT);
    const int jc = act ? j : 0;         // clamped index for safe loads

    const float* fb = feats + (size_t)b * LL * TT;
    const int*   mb = mask  + (size_t)b * LL;

    // Fwd needs E column j: Ecol[i] = E[i][j]. Bwd needs E row j: Erow[i] = E[j][i].
    // -1000 entries (START col / END row) become exact 0.
    float Ecol[TT], Erow[TT];
#pragma unroll
    for (int i = 0; i < TT; ++i) {
        float ec = __expf(trans[i * TT + jc]);
        float er = __expf(trans[jc * TT + i]);
        Ecol[i] = act ? ec : 0.0f;
        Erow[i] = act ? er : 0.0f;
    }

    // Forward init (t=0): part0[j] = feats[b,0,j] + trans[START][j]; normalize.
    float part0 = act ? (fb[j] + trans[(TT - 2) * TT + j]) : -1.0e30f;
    float shiftF = rl(part0, 0);
    float pvF = act ? __expf(part0 - shiftF) : 0.0f;

    // Backward init: w[i] = exp(trans[i][END])  (END row of E maps lane END -> 0)
    float wv = act ? __expf(trans[jc * TT + (TT - 1)]) : 0.0f;
    float shiftB = 0.0f;

    const float4* pqF = (const float4*)plds;
    const float4* pqB = (const float4*)(plds + 64);

    // Pair k: fwd t = 1+k, bwd t = 511-k, k = 0..254; then fwd-only t = 256.
    float fpF[NS], fpB[NS];
    int   mcF[NS], mcB[NS];
#pragma unroll
    for (int u = 0; u < NS; ++u) {
        fpF[u] = fb[(1 + u) * TT + jc];
        mcF[u] = mb[1 + u];
        fpB[u] = fb[(LL - 1 - u) * TT + jc];
        mcB[u] = mb[LL - 1 - u];
    }

    // Main loop: 31 groups of 8 pairs covering k = 0..247; tail k = 248..254.
    for (int g = 0; g + NS <= 248; g += NS) {
        // next group's loads first (8 pairs of latency slack)
        float fnF[NS], fnB[NS];
        int   mnF[NS], mnB[NS];
#pragma unroll
        for (int u = 0; u < NS; ++u) {
            int kn = g + NS + u;                 // <= 255 (k=255 -> fwd t=256 slot)
            fnF[u] = fb[(1 + kn) * TT + jc];
            mnF[u] = mb[1 + kn];
            fnB[u] = fb[(LL - 1 - kn) * TT + jc];
            mnB[u] = mb[LL - 1 - kn];
        }

        // ef for the whole group upfront: independent of both recurrence chains
        float efF[NS], efB[NS];
#pragma unroll
        for (int u = 0; u < NS; ++u) {
            efF[u] = __expf(fpF[u]);
            efB[u] = __expf(fpB[u]);
        }

#pragma unroll
        for (int u = 0; u < NS; ++u) {
            // broadcast current state at step start (in-order DS: prev step's
            // reads precede these writes; no sync, single buffer)
            plds[j]      = pvF;                  // fwd broadcasts p
            plds[64 + j] = efB[u] * wv;          // bwd broadcasts ef (*) w
            float a0 = 0.f, a1 = 0.f, a2 = 0.f, a3 = 0.f;
            float b0 = 0.f, b1 = 0.f, b2 = 0.f, b3 = 0.f;
#pragma unroll
            for (int kq = 0; kq < TT / 4; ++kq) {
                float4 qf = pqF[kq];
                float4 qb = pqB[kq];
                a0 = fmaf(qf.x, Ecol[4 * kq + 0], a0);
                a1 = fmaf(qf.y, Ecol[4 * kq + 1], a1);
                a2 = fmaf(qf.z, Ecol[4 * kq + 2], a2);
                a3 = fmaf(qf.w, Ecol[4 * kq + 3], a3);
                b0 = fmaf(qb.x, Erow[4 * kq + 0], b0);
                b1 = fmaf(qb.y, Erow[4 * kq + 1], b1);
                b2 = fmaf(qb.z, Erow[4 * kq + 2], b2);
                b3 = fmaf(qb.w, Erow[4 * kq + 3], b3);
            }
            float pnF = ((a0 + a1) + (a2 + a3)) * efF[u];
            float wnB = ((b0 + b1) + (b2 + b3));
            pvF = (mcF[u] > 0) ? pnF : pvF;      // branchless mask selects
            wv  = (mcB[u] > 0) ? wnB : wv;
            if (u == NS - 1) {
                // normalize both chains once per group by lane 0 (>0 always)
                float cF = rl(pvF, 0);
                float cB = rl(wv, 0);
                shiftF += __logf(cF);
                shiftB += __logf(cB);
                pvF *= __builtin_amdgcn_rcpf(cF);
                wv  *= __builtin_amdgcn_rcpf(cB);
            }
        }
#pragma unroll
        for (int u = 0; u < NS; ++u) {
            fpF[u] = fnF[u]; mcF[u] = mnF[u];
            fpB[u] = fnB[u]; mcB[u] = mnB[u];
        }
    }

    // Tail: 7 pairs, k = 248..254 (data already in fp*[0..6]).
#pragma unroll
    for (int u = 0; u < 7; ++u) {
        float efFu = __expf(fpF[u]);
        float efBu = __expf(fpB[u]);
        plds[j]      = pvF;
        plds[64 + j] = efBu * wv;
        float a0 = 0.f, a1 = 0.f, a2 = 0.f, a3 = 0.f;
        float b0 = 0.f, b1 = 0.f, b2 = 0.f, b3 = 0.f;
#pragma unroll
        for (int kq = 0; kq < TT / 4; ++kq) {
            float4 qf = pqF[kq];
            float4 qb = pqB[kq];
            a0 = fmaf(qf.x, Ecol[4 * kq + 0], a0);
            a1 = fmaf(qf.y, Ecol[4 * kq + 1], a1);
            a2 = fmaf(qf.z, Ecol[4 * kq + 2], a2);
            a3 = fmaf(qf.w, Ecol[4 * kq + 3], a3);
            b0 = fmaf(qb.x, Erow[4 * kq + 0], b0);
            b1 = fmaf(qb.y, Erow[4 * kq + 1], b1);
            b2 = fmaf(qb.z, Erow[4 * kq + 2], b2);
            b3 = fmaf(qb.w, Erow[4 * kq + 3], b3);
        }
        float pnF = ((a0 + a1) + (a2 + a3)) * efFu;
        float wnB = ((b0 + b1) + (b2 + b3));
        pvF = (mcF[u] > 0) ? pnF : pvF;
        wv  = (mcB[u] > 0) ? wnB : wv;
    }

    // Safety normalize before the final product (bounds pvF*wv away from inf).
    {
        float cF = rl(pvF, 0);
        float cB = rl(wv, 0);
        shiftF += __logf(cF);
        shiftB += __logf(cB);
        pvF *= __builtin_amdgcn_rcpf(cF);
        wv  *= __builtin_amdgcn_rcpf(cB);
    }

    // Final forward-only step t = 256 (k=255 slot prefetched in fp arrays).
    {
        float efFu = __expf(fpF[7]);
        plds[j] = pvF;
        float a0 = 0.f, a1 = 0.f, a2 = 0.f, a3 = 0.f;
#pragma unroll
        for (int kq = 0; kq < TT / 4; ++kq) {
            float4 qf = pqF[kq];
            a0 = fmaf(qf.x, Ecol[4 * kq + 0], a0);
            a1 = fmaf(qf.y, Ecol[4 * kq + 1], a1);
            a2 = fmaf(qf.z, Ecol[4 * kq + 2], a2);
            a3 = fmaf(qf.w, Ecol[4 * kq + 3], a3);
        }
        float pnF = ((a0 + a1) + (a2 + a3)) * efFu;
        pvF = (mcF[7] > 0) ? pnF : pvF;
    }

    // Combine: S = log(sum_i w[i] * u[i]) + shiftF + shiftB
    float val = act ? (pvF * wv) : 0.0f;
#pragma unroll
    for (int o = 32; o >= 1; o >>= 1)
        val += __shfl_xor(val, o, 64);
    if (j == 0) atomicAdd(out, __logf(val) + shiftF + shiftB);
}

extern "C" void kernel_launch(void* const* d_in, const int* in_sizes, int n_in,
                              void* d_out, int out_size, void* d_ws, size_t ws_size,
                              hipStream_t stream) {
    const float* feats = (const float*)d_in[0];
    const int*   mask  = (const int*)d_in[1];
    const float* trans = (const float*)d_in[2];
    float* out = (float*)d_out;

    const int B = in_sizes[1] / LL;   // mask is (B, L)

    hipMemsetAsync(d_out, 0, sizeof(float), stream);
    crf_fwd<<<B, 64, 0, stream>>>(feats, mask, trans, out);
}

// Round 3
// 213.656 us; speedup vs baseline: 1.1815x; 1.1399x over previous
//
#include <hip/hip_runtime.h>

// CRF forward partition, MI355X. B=1024, L=512, T=52.
//
// R9: fwd/bwd split across TWO WAVES (hardware TLP), not one instruction
// stream. R8 proved compiler-scheduled ILP gives ZERO overlap (pair cost
// 1230 cyc = 2x single-step 631; VGPR stuck at 132 => second chain likely
// spilled). Fix: block = 128 threads = 2 waves; wave 0 runs the forward
// chain t=1..256, wave 1 runs the backward chain t=511..257. 2048 waves on
// 1024 SIMDs = 2 waves/SIMD; the SIMD scheduler fills one wave's LDS
// round-trip + chain-latency stalls (~330 cyc/step) with the other wave's
// issue (~300 cyc/step). Each wave keeps the proven R7 structure: LDS
// broadcast (write 1 float, read back 13 uniform-address float4 quads,
// in-order DS => no sync), E in VGPRs, NS=8 prefetch groups, lane-0
// normalization once per group.
//
//   fwd:  u  = M_256...M_1 p0          (t = 1..256,   p'[j] = ef[j]*sum_i E[i][j] p[i])
//   bwd:  w <- E (ef_t (*) w)          (t = 511..257, w'[j] = sum_i E[j][i] ef[i] w[i])
//   out:  log(sum_j w[j]*u[j]) + shiftF + shiftB     (masked step = identity)

#define TT 52       // TAG_SIZE
#define LL 512      // sequence length
#define NS 8        // steps per group; normalize once per group
#define KSPLIT 256  // fwd covers t=1..KSPLIT; bwd covers t=KSPLIT+1..511

__device__ __forceinline__ float rl(float x, int lane) {
    return __int_as_float(__builtin_amdgcn_readlane(__float_as_int(x), lane));
}

__global__ void __launch_bounds__(128)
__attribute__((amdgpu_waves_per_eu(2, 2)))
crf_fwd(
    const float* __restrict__ feats,   // (B, L, T)
    const int*   __restrict__ mask,    // (B, L)
    const float* __restrict__ trans,   // (T, T)
    float*       __restrict__ out)     // scalar accumulator (pre-zeroed)
{
    __shared__ __align__(16) float plds[2][64];  // per-wave broadcast buffers
    __shared__ float shsh[2];                    // per-wave shift handoff

    const int b   = blockIdx.x;
    const int tid = threadIdx.x;
    const int w   = tid >> 6;           // 0 = fwd wave, 1 = bwd wave
    const int j   = tid & 63;           // lane = tag
    const bool act = (j < TT);
    const int jc = act ? j : 0;         // clamped index for safe loads

    const float* fb = feats + (size_t)b * LL * TT;
    const int*   mb = mask  + (size_t)b * LL;

    float pv;      // this wave's state vector entry (p[j] fwd / w[j] bwd)
    float shift;   // log of accumulated normalization factors

    if (w == 0) {
        // ---------------- forward chain: t = 1 .. 256 ----------------
        // E column j: Ecol[i] = exp(trans[i][j]); -1000 entries -> exact 0.
        float E[TT];
#pragma unroll
        for (int i = 0; i < TT; ++i) {
            float e = __expf(trans[i * TT + jc]);
            E[i] = act ? e : 0.0f;
        }

        // t=0 init: part0[j] = feats[b,0,j] + trans[START][j]; normalize.
        float part0 = act ? (fb[j] + trans[(TT - 2) * TT + j]) : -1.0e30f;
        shift = rl(part0, 0);
        pv = act ? __expf(part0 - shift) : 0.0f;
        plds[0][j] = pv;

        const float4* pq = (const float4*)plds[0];

        float fpre[NS]; int mc[NS];
#pragma unroll
        for (int u = 0; u < NS; ++u) {
            fpre[u] = fb[(1 + u) * TT + jc];
            mc[u]   = mb[1 + u];
        }

        // 32 groups of 8 covering t = 1..256 exactly (no tail).
        for (int t0 = 1; t0 + NS <= KSPLIT + 1; t0 += NS) {
            float fnx[NS]; int mn[NS];
#pragma unroll
            for (int u = 0; u < NS; ++u) {
                int tn = t0 + NS + u;            // <= 264 < LL, in-bounds
                fnx[u] = fb[tn * TT + jc];
                mn[u]  = mb[tn];
            }
            float ef[NS];
#pragma unroll
            for (int u = 0; u < NS; ++u) ef[u] = __expf(fpre[u]);

#pragma unroll
            for (int u = 0; u < NS; ++u) {
                float a0 = 0.f, a1 = 0.f, a2 = 0.f, a3 = 0.f;
#pragma unroll
                for (int kq = 0; kq < TT / 4; ++kq) {
                    float4 q = pq[kq];
                    a0 = fmaf(q.x, E[4 * kq + 0], a0);
                    a1 = fmaf(q.y, E[4 * kq + 1], a1);
                    a2 = fmaf(q.z, E[4 * kq + 2], a2);
                    a3 = fmaf(q.w, E[4 * kq + 3], a3);
                }
                float pn = ((a0 + a1) + (a2 + a3)) * ef[u];
                pv = (mc[u] > 0) ? pn : pv;      // branchless mask select
                if (u == NS - 1) {
                    float c = rl(pv, 0);
                    shift += __logf(c);
                    pv *= __builtin_amdgcn_rcpf(c);
                }
                plds[0][j] = pv;                 // broadcast for next step
            }
#pragma unroll
            for (int u = 0; u < NS; ++u) { fpre[u] = fnx[u]; mc[u] = mn[u]; }
        }
    } else {
        // ---------------- backward chain: t = 511 .. 257 ----------------
        // E row j: Erow[i] = exp(trans[j][i]); -1000 entries -> exact 0.
        float E[TT];
#pragma unroll
        for (int i = 0; i < TT; ++i) {
            float e = __expf(trans[jc * TT + i]);
            E[i] = act ? e : 0.0f;
        }

        // init: w[j] = exp(trans[j][END])
        pv = act ? __expf(trans[jc * TT + (TT - 1)]) : 0.0f;
        shift = 0.0f;

        const float4* pq = (const float4*)plds[1];

        // k = 0..254 maps to t = 511-k (t = 511..257).
        float fpre[NS]; int mc[NS];
#pragma unroll
        for (int u = 0; u < NS; ++u) {
            fpre[u] = fb[(LL - 1 - u) * TT + jc];
            mc[u]   = mb[LL - 1 - u];
        }

        // 31 groups of 8 covering k = 0..247; tail k = 248..254.
        for (int g = 0; g + NS <= 248; g += NS) {
            float fnx[NS]; int mn[NS];
#pragma unroll
            for (int u = 0; u < NS; ++u) {
                int kn = g + NS + u;             // <= 255 -> t >= 256, in-bounds
                fnx[u] = fb[(LL - 1 - kn) * TT + jc];
                mn[u]  = mb[LL - 1 - kn];
            }
            float ef[NS];
#pragma unroll
            for (int u = 0; u < NS; ++u) ef[u] = __expf(fpre[u]);

#pragma unroll
            for (int u = 0; u < NS; ++u) {
                plds[1][j] = ef[u] * pv;         // broadcast ef (*) w
                float a0 = 0.f, a1 = 0.f, a2 = 0.f, a3 = 0.f;
#pragma unroll
                for (int kq = 0; kq < TT / 4; ++kq) {
                    float4 q = pq[kq];
                    a0 = fmaf(q.x, E[4 * kq + 0], a0);
                    a1 = fmaf(q.y, E[4 * kq + 1], a1);
                    a2 = fmaf(q.z, E[4 * kq + 2], a2);
                    a3 = fmaf(q.w, E[4 * kq + 3], a3);
                }
                float pn = ((a0 + a1) + (a2 + a3));
                pv = (mc[u] > 0) ? pn : pv;      // branchless mask select
                if (u == NS - 1) {
                    float c = rl(pv, 0);
                    shift += __logf(c);
                    pv *= __builtin_amdgcn_rcpf(c);
                }
            }
#pragma unroll
            for (int u = 0; u < NS; ++u) { fpre[u] = fnx[u]; mc[u] = mn[u]; }
        }

        // Tail: 7 steps, k = 248..254 (data already in fpre[0..6]).
#pragma unroll
        for (int u = 0; u < 7; ++u) {
            float efu = __expf(fpre[u]);
            plds[1][j] = efu * pv;
            float a0 = 0.f, a1 = 0.f, a2 = 0.f, a3 = 0.f;
#pragma unroll
            for (int kq = 0; kq < TT / 4; ++kq) {
                float4 q = pq[kq];
                a0 = fmaf(q.x, E[4 * kq + 0], a0);
                a1 = fmaf(q.y, E[4 * kq + 1], a1);
                a2 = fmaf(q.z, E[4 * kq + 2], a2);
                a3 = fmaf(q.w, E[4 * kq + 3], a3);
            }
            float pn = ((a0 + a1) + (a2 + a3));
            pv = (mc[u] > 0) ? pn : pv;
        }

        // Final safety normalize (bounds w away from inf before combine).
        {
            float c = rl(pv, 0);
            shift += __logf(c);
            pv *= __builtin_amdgcn_rcpf(c);
        }
    }

    // ---------------- combine: S = log(sum_j w[j]*u[j]) + shiftF + shiftB ----
    plds[w][j] = pv;
    if (j == 0) shsh[w] = shift;
    __syncthreads();

    if (w == 0) {
        float wj  = plds[1][j];                  // bwd vector (0 for j >= TT)
        float val = act ? (pv * wj) : 0.0f;
#pragma unroll
        for (int o = 32; o >= 1; o >>= 1)
            val += __shfl_xor(val, o, 64);
        if (j == 0) atomicAdd(out, __logf(val) + shift + shsh[1]);
    }
}

extern "C" void kernel_launch(void* const* d_in, const int* in_sizes, int n_in,
                              void* d_out, int out_size, void* d_ws, size_t ws_size,
                              hipStream_t stream) {
    const float* feats = (const float*)d_in[0];
    const int*   mask  = (const int*)d_in[1];
    const float* trans = (const float*)d_in[2];
    float* out = (float*)d_out;

    const int B = in_sizes[1] / LL;   // mask is (B, L)

    hipMemsetAsync(d_out, 0, sizeof(float), stream);
    crf_fwd<<<B, 128, 0, stream>>>(feats, mask, trans, out);
}

// Round 4
// 200.876 us; speedup vs baseline: 1.2566x; 1.0636x over previous
//
#include <hip/hip_runtime.h>

// CRF forward partition, MI355X. B=1024, L=512, T=52.
//
// R10 = R9 (fwd/bwd chains on 2 waves/block, 2 waves/SIMD) + issue diet:
//  - v_pk_fma_f32: 52 scalar fmacs -> 26 packed (gfx90a+ packed fp32).
//    4 packed accumulators also cut dependent-chain depth 13 -> ~7.
//  - ping-pong prefetch buffers (two group bodies per outer iter) kill the
//    32 v_mov group-edge copies.
// R9 evidence: 482 cyc/step-slot, VALUBusy 65% (=2x150 issue cyc/wave-step),
// ~170 cyc dual-stall. Issue cuts now pay because the other wave can absorb
// freed slots (unlike R7's 1-wave regime where they just became stalls).
//
//   fwd:  u  = M_256...M_1 p0          (t = 1..256,   p'[j] = ef[j]*sum_i E[i][j] p[i])
//   bwd:  w <- E (ef_t (*) w)          (t = 511..257, w'[j] = sum_i E[j][i] ef[i] w[i])
//   out:  log(sum_j w[j]*u[j]) + shiftF + shiftB     (masked step = identity)

#define TT 52       // TAG_SIZE
#define LL 512      // sequence length
#define NS 8        // steps per group; normalize once per group
#define KSPLIT 256  // fwd covers t=1..KSPLIT; bwd covers t=KSPLIT+1..511

typedef float v2f __attribute__((ext_vector_type(2)));

__device__ __forceinline__ v2f pkfma(v2f a, v2f b, v2f c) {
#if __has_builtin(__builtin_elementwise_fma)
    return __builtin_elementwise_fma(a, b, c);   // lowers to v_pk_fma_f32
#else
    v2f r; r.x = fmaf(a.x, b.x, c.x); r.y = fmaf(a.y, b.y, c.y); return r;
#endif
}

__device__ __forceinline__ float rl(float x, int lane) {
    return __int_as_float(__builtin_amdgcn_readlane(__float_as_int(x), lane));
}

// One matvec vs packed coefficient array E2[26] using LDS quads at pq.
// Returns sum_i E[i]*p[i] with 8 scalar chains (4 packed accumulators).
__device__ __forceinline__ float matvec52(const float4* pq, const v2f* E2) {
    v2f ae0 = {0.f, 0.f}, ae1 = {0.f, 0.f};
    v2f ao0 = {0.f, 0.f}, ao1 = {0.f, 0.f};
#pragma unroll
    for (int kq = 0; kq < TT / 4; ++kq) {
        float4 q = pq[kq];
        v2f lo = {q.x, q.y};
        v2f hi = {q.z, q.w};
        if ((kq & 1) == 0) {
            ae0 = pkfma(lo, E2[2 * kq + 0], ae0);
            ae1 = pkfma(hi, E2[2 * kq + 1], ae1);
        } else {
            ao0 = pkfma(lo, E2[2 * kq + 0], ao0);
            ao1 = pkfma(hi, E2[2 * kq + 1], ao1);
        }
    }
    v2f s = (ae0 + ao0) + (ae1 + ao1);
    return s.x + s.y;
}

__global__ void __launch_bounds__(128)
__attribute__((amdgpu_waves_per_eu(2, 2)))
crf_fwd(
    const float* __restrict__ feats,   // (B, L, T)
    const int*   __restrict__ mask,    // (B, L)
    const float* __restrict__ trans,   // (T, T)
    float*       __restrict__ out)     // scalar accumulator (pre-zeroed)
{
    __shared__ __align__(16) float plds[2][64];  // per-wave broadcast buffers
    __shared__ float shsh[2];                    // per-wave shift handoff

    const int b   = blockIdx.x;
    const int tid = threadIdx.x;
    const int w   = tid >> 6;           // 0 = fwd wave, 1 = bwd wave
    const int j   = tid & 63;           // lane = tag
    const bool act = (j < TT);
    const int jc = act ? j : 0;         // clamped index for safe loads

    const float* fb = feats + (size_t)b * LL * TT;
    const int*   mb = mask  + (size_t)b * LL;

    float pv;      // this wave's state vector entry (p[j] fwd / w[j] bwd)
    float shift;   // log of accumulated normalization factors

    if (w == 0) {
        // ---------------- forward chain: t = 1 .. 256 ----------------
        // E column j packed: E2[k] = {exp(trans[2k][j]), exp(trans[2k+1][j])}.
        v2f E2[TT / 2];
#pragma unroll
        for (int k = 0; k < TT / 2; ++k) {
            float e0 = __expf(trans[(2 * k + 0) * TT + jc]);
            float e1 = __expf(trans[(2 * k + 1) * TT + jc]);
            E2[k].x = act ? e0 : 0.0f;
            E2[k].y = act ? e1 : 0.0f;
        }

        // t=0 init: part0[j] = feats[b,0,j] + trans[START][j]; normalize.
        float part0 = act ? (fb[j] + trans[(TT - 2) * TT + j]) : -1.0e30f;
        shift = rl(part0, 0);
        pv = act ? __expf(part0 - shift) : 0.0f;
        plds[0][j] = pv;

        const float4* pq = (const float4*)plds[0];

        float fA[NS], fB[NS]; int mA[NS], mB[NS];
#pragma unroll
        for (int u = 0; u < NS; ++u) {
            fA[u] = fb[(1 + u) * TT + jc];
            mA[u] = mb[1 + u];
        }

        // Group body: consume fp/mc, prefetch next group into fn/mn.
        auto fwd_group = [&](float (&fp)[NS], int (&mc)[NS],
                             float (&fn)[NS], int (&mn)[NS], int t0) {
#pragma unroll
            for (int u = 0; u < NS; ++u) {
                int tn = t0 + NS + u;            // <= 264 < LL, in-bounds
                fn[u] = fb[tn * TT + jc];
                mn[u] = mb[tn];
            }
            float ef[NS];
#pragma unroll
            for (int u = 0; u < NS; ++u) ef[u] = __expf(fp[u]);
#pragma unroll
            for (int u = 0; u < NS; ++u) {
                float pn = matvec52(pq, E2) * ef[u];
                pv = (mc[u] > 0) ? pn : pv;      // branchless mask select
                if (u == NS - 1) {
                    float c = rl(pv, 0);
                    shift += __logf(c);
                    pv *= __builtin_amdgcn_rcpf(c);
                }
                plds[0][j] = pv;                 // broadcast for next step
            }
        };

        // 32 groups (t0 = 1..249) as 16 ping-pong pairs: t = 1..256 exactly.
        for (int t0 = 1; t0 <= 241; t0 += 2 * NS) {
            fwd_group(fA, mA, fB, mB, t0);
            fwd_group(fB, mB, fA, mA, t0 + NS);
        }
    } else {
        // ---------------- backward chain: t = 511 .. 257 ----------------
        // E row j packed: E2[k] = {exp(trans[j][2k]), exp(trans[j][2k+1])}.
        v2f E2[TT / 2];
#pragma unroll
        for (int k = 0; k < TT / 2; ++k) {
            float e0 = __expf(trans[jc * TT + 2 * k + 0]);
            float e1 = __expf(trans[jc * TT + 2 * k + 1]);
            E2[k].x = act ? e0 : 0.0f;
            E2[k].y = act ? e1 : 0.0f;
        }

        // init: w[j] = exp(trans[j][END])
        pv = act ? __expf(trans[jc * TT + (TT - 1)]) : 0.0f;
        shift = 0.0f;

        const float4* pq = (const float4*)plds[1];

        // k = 0..254 maps to t = 511-k (t = 511..257).
        float fA[NS], fB[NS]; int mA[NS], mB[NS];
#pragma unroll
        for (int u = 0; u < NS; ++u) {
            fA[u] = fb[(LL - 1 - u) * TT + jc];
            mA[u] = mb[LL - 1 - u];
        }

        auto bwd_group = [&](float (&fp)[NS], int (&mc)[NS],
                             float (&fn)[NS], int (&mn)[NS], int g) {
#pragma unroll
            for (int u = 0; u < NS; ++u) {
                int kn = g + NS + u;             // <= 255 -> t >= 256, in-bounds
                fn[u] = fb[(LL - 1 - kn) * TT + jc];
                mn[u] = mb[LL - 1 - kn];
            }
            float ef[NS];
#pragma unroll
            for (int u = 0; u < NS; ++u) ef[u] = __expf(fp[u]);
#pragma unroll
            for (int u = 0; u < NS; ++u) {
                plds[1][j] = ef[u] * pv;         // broadcast ef (*) w
                float pn = matvec52(pq, E2);
                pv = (mc[u] > 0) ? pn : pv;      // branchless mask select
                if (u == NS - 1) {
                    float c = rl(pv, 0);
                    shift += __logf(c);
                    pv *= __builtin_amdgcn_rcpf(c);
                }
            }
        };

        // 30 groups as 15 ping-pong pairs (k = 0..239), 1 single group
        // (k = 240..247, prefetches k = 248..255 into fB), then 7-step tail.
        for (int g = 0; g <= 224; g += 2 * NS) {
            bwd_group(fA, mA, fB, mB, g);
            bwd_group(fB, mB, fA, mA, g + NS);
        }
        bwd_group(fA, mA, fB, mB, 240);

        // Tail: 7 steps, k = 248..254 (data in fB[0..6]).
#pragma unroll
        for (int u = 0; u < 7; ++u) {
            float efu = __expf(fB[u]);
            plds[1][j] = efu * pv;
            float pn = matvec52(pq, E2);
            pv = (mB[u] > 0) ? pn : pv;
        }

        // Final safety normalize (bounds w away from inf before combine).
        {
            float c = rl(pv, 0);
            shift += __logf(c);
            pv *= __builtin_amdgcn_rcpf(c);
        }
    }

    // ---------------- combine: S = log(sum_j w[j]*u[j]) + shiftF + shiftB ----
    plds[w][j] = pv;
    if (j == 0) shsh[w] = shift;
    __syncthreads();

    if (w == 0) {
        float wj  = plds[1][j];                  // bwd vector (0 for j >= TT)
        float val = act ? (pv * wj) : 0.0f;
#pragma unroll
        for (int o = 32; o >= 1; o >>= 1)
            val += __shfl_xor(val, o, 64);
        if (j == 0) atomicAdd(out, __logf(val) + shift + shsh[1]);
    }
}

extern "C" void kernel_launch(void* const* d_in, const int* in_sizes, int n_in,
                              void* d_out, int out_size, void* d_ws, size_t ws_size,
                              hipStream_t stream) {
    const float* feats = (const float*)d_in[0];
    const int*   mask  = (const int*)d_in[1];
    const float* trans = (const float*)d_in[2];
    float* out = (float*)d_out;

    const int B = in_sizes[1] / LL;   // mask is (B, L)

    hipMemsetAsync(d_out, 0, sizeof(float), stream);
    crf_fwd<<<B, 128, 0, stream>>>(feats, mask, trans, out);
}